// Round 1
// baseline (777.752 us; speedup 1.0000x reference)
//
#include <hip/hip_runtime.h>
#include <hip/hip_bf16.h>

// Problem constants
#define B_  2
#define T_  2048
#define D_  1024
#define H_  16
#define DH_ 64
#define M_  (B_*T_)      // 4096 rows for the big GEMMs

typedef __bf16 bf16;
typedef __bf16 bf16x8 __attribute__((ext_vector_type(8)));
typedef __bf16 bf16x4 __attribute__((ext_vector_type(4)));
typedef float  f32x4  __attribute__((ext_vector_type(4)));

// ---------------------------------------------------------------------------
// LayerNorm: one block per row (1024 floats), 3 sources selected by blockIdx.y
// ---------------------------------------------------------------------------
__global__ __launch_bounds__(256) void ln_kernel(
    const float* __restrict__ xq, const float* __restrict__ xk,
    const float* __restrict__ xv, const float* __restrict__ gamma,
    const float* __restrict__ beta,
    bf16* __restrict__ oq, bf16* __restrict__ ok, bf16* __restrict__ ov)
{
    const int row = blockIdx.x;
    const int sel = blockIdx.y;
    const float* x = (sel == 0 ? xq : sel == 1 ? xk : xv) + (size_t)row * D_;
    bf16*        o = (sel == 0 ? oq : sel == 1 ? ok : ov) + (size_t)row * D_;
    const int tid = threadIdx.x;

    float4 v = *(const float4*)&x[tid * 4];
    float s  = v.x + v.y + v.z + v.w;
    float s2 = v.x*v.x + v.y*v.y + v.z*v.z + v.w*v.w;
    for (int off = 32; off > 0; off >>= 1) {
        s  += __shfl_down(s,  off, 64);
        s2 += __shfl_down(s2, off, 64);
    }
    __shared__ float red[8];
    const int wave = tid >> 6, lane = tid & 63;
    if (lane == 0) { red[wave] = s; red[4 + wave] = s2; }
    __syncthreads();
    s  = red[0] + red[1] + red[2] + red[3];
    s2 = red[4] + red[5] + red[6] + red[7];
    const float mu   = s * (1.0f / D_);
    const float var  = s2 * (1.0f / D_) - mu * mu;
    const float rstd = rsqrtf(var + 1e-5f);

    float4 g  = *(const float4*)&gamma[tid * 4];
    float4 bb = *(const float4*)&beta[tid * 4];
    bf16x4 o4;
    o4[0] = (bf16)((v.x - mu) * rstd * g.x + bb.x);
    o4[1] = (bf16)((v.y - mu) * rstd * g.y + bb.y);
    o4[2] = (bf16)((v.z - mu) * rstd * g.z + bb.z);
    o4[3] = (bf16)((v.w - mu) * rstd * g.w + bb.w);
    *(bf16x4*)&o[tid * 4] = o4;
}

// ---------------------------------------------------------------------------
// Weight convert + transpose: W[k][n] fp32 -> Wt[n][k] bf16 (1024x1024 each)
// ---------------------------------------------------------------------------
__global__ __launch_bounds__(256) void wconv_kernel(
    const float* __restrict__ Wq, const float* __restrict__ Wk,
    const float* __restrict__ Wv, const float* __restrict__ Wo,
    bf16* __restrict__ wqt, bf16* __restrict__ wkt,
    bf16* __restrict__ wvt, bf16* __restrict__ wot)
{
    const float* Ws[4] = {Wq, Wk, Wv, Wo};
    bf16*        Wt[4] = {wqt, wkt, wvt, wot};
    const float* W = Ws[blockIdx.z];
    bf16*        O = Wt[blockIdx.z];
    const int n0 = blockIdx.x * 32, k0 = blockIdx.y * 32;
    __shared__ float tile[32][33];
    const int tid = threadIdx.x;
    #pragma unroll
    for (int i = 0; i < 4; i++) {
        int e = tid + i * 256;
        int r = e >> 5, c = e & 31;
        tile[r][c] = W[(size_t)(k0 + r) * 1024 + n0 + c];
    }
    __syncthreads();
    #pragma unroll
    for (int i = 0; i < 4; i++) {
        int e = tid + i * 256;
        int nr = e >> 5, kc = e & 31;
        O[(size_t)(n0 + nr) * 1024 + k0 + kc] = (bf16)tile[kc][nr];
    }
}

// ---------------------------------------------------------------------------
// GEMM: C[M,N] = A[M,K] @ Bt[N,K]^T + bias.  M=4096, N=K=1024.
// 128x128 tile / block (256 thr, 4 waves in 2x2, each wave 64x64 = 4x4 MFMA).
// MODE 0: headed bf16 output [B][H][T][DH];  MODE 1: row-major fp32 output.
// ---------------------------------------------------------------------------
template <int MODE>
__global__ __launch_bounds__(256) void gemm_bt(
    const bf16* __restrict__ A, const bf16* __restrict__ Bt,
    const float* __restrict__ bias, void* __restrict__ Cout)
{
    __shared__ bf16 sA[128][40];   // pad 32->40 (80B stride, 16B aligned)
    __shared__ bf16 sB[128][40];
    const int tid  = threadIdx.x;
    const int wave = tid >> 6, lane = tid & 63;
    const int quad = lane >> 4, l16 = lane & 15;
    const int wr = (wave >> 1) * 64, wc = (wave & 1) * 64;
    const int m0 = blockIdx.y * 128, n0 = blockIdx.x * 128;

    f32x4 acc[4][4] = {};
    const int r0   = tid >> 2;          // rows 0..63
    const int r1   = 64 + (tid >> 2);   // rows 64..127
    const int off0 = (tid & 3) * 8;     // 0,8,16,24

    for (int k0 = 0; k0 < 1024; k0 += 32) {
        __syncthreads();
        *(bf16x8*)&sA[r0][off0] = *(const bf16x8*)&A[(size_t)(m0 + r0) * 1024 + k0 + off0];
        *(bf16x8*)&sA[r1][off0] = *(const bf16x8*)&A[(size_t)(m0 + r1) * 1024 + k0 + off0];
        *(bf16x8*)&sB[r0][off0] = *(const bf16x8*)&Bt[(size_t)(n0 + r0) * 1024 + k0 + off0];
        *(bf16x8*)&sB[r1][off0] = *(const bf16x8*)&Bt[(size_t)(n0 + r1) * 1024 + k0 + off0];
        __syncthreads();

        bf16x8 af[4], bfr[4];
        #pragma unroll
        for (int i = 0; i < 4; i++) af[i]  = *(bf16x8*)&sA[wr + i * 16 + l16][quad * 8];
        #pragma unroll
        for (int j = 0; j < 4; j++) bfr[j] = *(bf16x8*)&sB[wc + j * 16 + l16][quad * 8];
        #pragma unroll
        for (int i = 0; i < 4; i++)
            #pragma unroll
            for (int j = 0; j < 4; j++)
                acc[i][j] = __builtin_amdgcn_mfma_f32_16x16x32_bf16(af[i], bfr[j], acc[i][j], 0, 0, 0);
    }

    #pragma unroll
    for (int i = 0; i < 4; i++) {
        #pragma unroll
        for (int j = 0; j < 4; j++) {
            const int n = n0 + wc + j * 16 + l16;
            const float bia = bias[n];
            #pragma unroll
            for (int r = 0; r < 4; r++) {
                const int m = m0 + wr + i * 16 + quad * 4 + r;
                const float v = acc[i][j][r] + bia;
                if (MODE == 0) {
                    const int b = m >> 11, t = m & 2047, h = n >> 6, dh = n & 63;
                    ((bf16*)Cout)[(((size_t)b * H_ + h) * T_ + t) * DH_ + dh] = (bf16)v;
                } else {
                    ((float*)Cout)[(size_t)m * 1024 + n] = v;
                }
            }
        }
    }
}

// ---------------------------------------------------------------------------
// Fused attention, two sweeps per 64-query block (grid: x = T/64, y = B*H).
// Sweep 1: online row max/sum over valid key tiles (no score materialization).
// Sweep 2: recompute S, write normalized attn (fp32) to d_out, P@V via MFMA
//          (P round-trips through LDS: C/D layout -> A-operand layout).
// ---------------------------------------------------------------------------
__global__ __launch_bounds__(256) void attn_kernel(
    const bf16* __restrict__ Qh, const bf16* __restrict__ Kh,
    const bf16* __restrict__ Vh, const int* __restrict__ lens,
    float* __restrict__ attn_out, bf16* __restrict__ Obuf)
{
    const int bh = blockIdx.y;
    const int b = bh >> 4, h = bh & 15;
    const int bx = blockIdx.x;
    const int q0 = bx * 64;
    const int len = lens[b];
    const bf16* Qp = Qh + (size_t)bh * T_ * DH_;
    const bf16* Kp = Kh + (size_t)bh * T_ * DH_;
    const bf16* Vp = Vh + (size_t)bh * T_ * DH_;
    float* attnp = attn_out + (size_t)bh * T_ * T_;

    const int tid  = threadIdx.x;
    const int wave = tid >> 6, lane = tid & 63;
    const int quad = lane >> 4, l16 = lane & 15;
    const float scale = 0.125f;   // 1/sqrt(64)

    __shared__ bf16 Kt[64][72];        // [key][dh], pad 64->72
    __shared__ bf16 Vt[64][72];        // [dh][key], pad
    __shared__ bf16 Pt[4][16][72];     // per-wave P tile [q][key], pad

    // Q fragments (A-operand: m = l16, k = quad*8+j), direct from global
    const int qrow = q0 + wave * 16 + l16;
    const bf16x8 aq0 = *(const bf16x8*)&Qp[(size_t)qrow * DH_ + quad * 8];
    const bf16x8 aq1 = *(const bf16x8*)&Qp[(size_t)qrow * DH_ + 32 + quad * 8];

    const int jb_hi = min(bx, (len - 1) >> 6);   // last key tile with any valid key

    // staging geometry: 64 rows x 64 bf16 = 512 16B-segments / 256 threads
    const int krow0 = tid >> 3;            // 0..31
    const int krow1 = 32 + (tid >> 3);     // 32..63
    const int koff0 = (tid & 7) * 8;

    float mrow[4], lrow[4];
    #pragma unroll
    for (int r = 0; r < 4; r++) { mrow[r] = -INFINITY; lrow[r] = 0.0f; }

    // ---------------- Sweep 1: row statistics ----------------
    for (int jb = 0; jb <= jb_hi; jb++) {
        __syncthreads();
        *(bf16x8*)&Kt[krow0][koff0] = *(const bf16x8*)&Kp[(size_t)(jb * 64 + krow0) * DH_ + koff0];
        *(bf16x8*)&Kt[krow1][koff0] = *(const bf16x8*)&Kp[(size_t)(jb * 64 + krow1) * DH_ + koff0];
        __syncthreads();

        f32x4 sc[4];
        #pragma unroll
        for (int c = 0; c < 4; c++) {
            bf16x8 b0 = *(bf16x8*)&Kt[c * 16 + l16][quad * 8];
            bf16x8 b1 = *(bf16x8*)&Kt[c * 16 + l16][32 + quad * 8];
            f32x4 s = {};
            s = __builtin_amdgcn_mfma_f32_16x16x32_bf16(aq0, b0, s, 0, 0, 0);
            s = __builtin_amdgcn_mfma_f32_16x16x32_bf16(aq1, b1, s, 0, 0, 0);
            sc[c] = s;
        }
        #pragma unroll
        for (int r = 0; r < 4; r++) {
            const int t_g = q0 + wave * 16 + quad * 4 + r;
            float sv[4];
            float tmax = -INFINITY;
            #pragma unroll
            for (int c = 0; c < 4; c++) {
                const int k_g = jb * 64 + c * 16 + l16;
                const bool valid = (k_g <= t_g) && (k_g < len);
                sv[c] = valid ? sc[c][r] * scale : -INFINITY;
                tmax = fmaxf(tmax, sv[c]);
            }
            #pragma unroll
            for (int o = 1; o < 16; o <<= 1) tmax = fmaxf(tmax, __shfl_xor(tmax, o, 16));
            const float newm = fmaxf(mrow[r], tmax);   // finite after jb=0 (key 0 always valid)
            float psum = 0.0f;
            #pragma unroll
            for (int c = 0; c < 4; c++) psum += __expf(sv[c] - newm);  // expf(-inf)=0
            #pragma unroll
            for (int o = 1; o < 16; o <<= 1) psum += __shfl_xor(psum, o, 16);
            lrow[r] = lrow[r] * __expf(mrow[r] - newm) + psum;
            mrow[r] = newm;
        }
    }

    float linv[4];
    #pragma unroll
    for (int r = 0; r < 4; r++) linv[r] = 1.0f / lrow[r];

    // ---------------- Sweep 2: attn write + P@V ----------------
    f32x4 oacc[4] = {};
    for (int jb = 0; jb <= jb_hi; jb++) {
        __syncthreads();
        *(bf16x8*)&Kt[krow0][koff0] = *(const bf16x8*)&Kp[(size_t)(jb * 64 + krow0) * DH_ + koff0];
        *(bf16x8*)&Kt[krow1][koff0] = *(const bf16x8*)&Kp[(size_t)(jb * 64 + krow1) * DH_ + koff0];
        {   // V tile, transposed into Vt[dh][key]
            bf16x8 v0 = *(const bf16x8*)&Vp[(size_t)(jb * 64 + krow0) * DH_ + koff0];
            bf16x8 v1 = *(const bf16x8*)&Vp[(size_t)(jb * 64 + krow1) * DH_ + koff0];
            #pragma unroll
            for (int j2 = 0; j2 < 8; j2++) {
                Vt[koff0 + j2][krow0] = v0[j2];
                Vt[koff0 + j2][krow1] = v1[j2];
            }
        }
        __syncthreads();

        f32x4 sc[4];
        #pragma unroll
        for (int c = 0; c < 4; c++) {
            bf16x8 b0 = *(bf16x8*)&Kt[c * 16 + l16][quad * 8];
            bf16x8 b1 = *(bf16x8*)&Kt[c * 16 + l16][32 + quad * 8];
            f32x4 s = {};
            s = __builtin_amdgcn_mfma_f32_16x16x32_bf16(aq0, b0, s, 0, 0, 0);
            s = __builtin_amdgcn_mfma_f32_16x16x32_bf16(aq1, b1, s, 0, 0, 0);
            sc[c] = s;
        }
        #pragma unroll
        for (int c = 0; c < 4; c++) {
            const int k_g = jb * 64 + c * 16 + l16;
            #pragma unroll
            for (int r = 0; r < 4; r++) {
                const int t_g = q0 + wave * 16 + quad * 4 + r;
                const bool valid = (k_g <= t_g) && (k_g < len);
                const float p = valid ? __expf(sc[c][r] * scale - mrow[r]) * linv[r] : 0.0f;
                attnp[(size_t)t_g * T_ + k_g] = p;
                Pt[wave][quad * 4 + r][c * 16 + l16] = (bf16)p;
            }
        }
        // make this wave's Pt writes visible to its own ds_reads
        asm volatile("s_waitcnt lgkmcnt(0)" ::: "memory");
        #pragma unroll
        for (int ks = 0; ks < 2; ks++) {
            bf16x8 ap = *(bf16x8*)&Pt[wave][l16][ks * 32 + quad * 8];
            #pragma unroll
            for (int c = 0; c < 4; c++) {
                bf16x8 vb = *(bf16x8*)&Vt[c * 16 + l16][ks * 32 + quad * 8];
                oacc[c] = __builtin_amdgcn_mfma_f32_16x16x32_bf16(ap, vb, oacc[c], 0, 0, 0);
            }
        }
    }

    // Zero-fill the columns beyond the last computed key tile (coalesced float4)
    const int zc0 = (jb_hi + 1) * 64;
    if (zc0 < T_) {
        const int span4 = (T_ - zc0) >> 2;
        for (int r = 0; r < 16; r++) {
            const size_t rowbase = (size_t)(q0 + wave * 16 + r) * T_ + zc0;
            for (int c4 = lane; c4 < span4; c4 += 64) {
                *(float4*)&attnp[rowbase + (size_t)c4 * 4] = make_float4(0.f, 0.f, 0.f, 0.f);
            }
        }
    }

    // Write O (bf16) in [b][t][h*64+dh] layout for the output GEMM
    #pragma unroll
    for (int c = 0; c < 4; c++) {
        #pragma unroll
        for (int r = 0; r < 4; r++) {
            const int t_g = q0 + wave * 16 + quad * 4 + r;
            const int dh = c * 16 + l16;
            Obuf[(size_t)(b * T_ + t_g) * 1024 + h * DH_ + dh] = (bf16)oacc[c][r];
        }
    }
}

// ---------------------------------------------------------------------------
extern "C" void kernel_launch(void* const* d_in, const int* in_sizes, int n_in,
                              void* d_out, int out_size, void* d_ws, size_t ws_size,
                              hipStream_t stream)
{
    const float* xq    = (const float*)d_in[0];
    const float* xk    = (const float*)d_in[1];
    const float* xv    = (const float*)d_in[2];
    const int*   lens  = (const int*)d_in[3];
    const float* Wq    = (const float*)d_in[4];
    const float* bq    = (const float*)d_in[5];
    const float* Wk    = (const float*)d_in[6];
    const float* bk    = (const float*)d_in[7];
    const float* Wv    = (const float*)d_in[8];
    const float* bv    = (const float*)d_in[9];
    const float* Wo    = (const float*)d_in[10];
    const float* bo    = (const float*)d_in[11];
    const float* gamma = (const float*)d_in[12];
    const float* beta  = (const float*)d_in[13];

    float* out      = (float*)d_out;
    float* attn_out = out + (size_t)M_ * D_;   // attn_viz region [B*H][T][T]

    // workspace carve-up (~64 MB total)
    char* ws = (char*)d_ws;
    bf16* lnq  = (bf16*)ws; ws += (size_t)M_ * D_ * 2;
    bf16* lnk  = (bf16*)ws; ws += (size_t)M_ * D_ * 2;
    bf16* lnv  = (bf16*)ws; ws += (size_t)M_ * D_ * 2;
    bf16* wqt  = (bf16*)ws; ws += (size_t)1024 * 1024 * 2;
    bf16* wkt  = (bf16*)ws; ws += (size_t)1024 * 1024 * 2;
    bf16* wvt  = (bf16*)ws; ws += (size_t)1024 * 1024 * 2;
    bf16* wot  = (bf16*)ws; ws += (size_t)1024 * 1024 * 2;
    bf16* Qh   = (bf16*)ws; ws += (size_t)M_ * D_ * 2;   // [B][H][T][DH]
    bf16* Kh   = (bf16*)ws; ws += (size_t)M_ * D_ * 2;
    bf16* Vh   = (bf16*)ws; ws += (size_t)M_ * D_ * 2;
    bf16* Obuf = (bf16*)ws; ws += (size_t)M_ * D_ * 2;   // [B][T][H*DH]

    ln_kernel<<<dim3(M_, 3), 256, 0, stream>>>(xq, xk, xv, gamma, beta, lnq, lnk, lnv);
    wconv_kernel<<<dim3(32, 32, 4), 256, 0, stream>>>(Wq, Wk, Wv, Wo, wqt, wkt, wvt, wot);
    gemm_bt<0><<<dim3(8, 32), 256, 0, stream>>>(lnq, wqt, bq, (void*)Qh);
    gemm_bt<0><<<dim3(8, 32), 256, 0, stream>>>(lnk, wkt, bk, (void*)Kh);
    gemm_bt<0><<<dim3(8, 32), 256, 0, stream>>>(lnv, wvt, bv, (void*)Vh);
    attn_kernel<<<dim3(T_ / 64, B_ * H_), 256, 0, stream>>>(Qh, Kh, Vh, lens, attn_out, Obuf);
    gemm_bt<1><<<dim3(8, 32), 256, 0, stream>>>(Obuf, wot, bo, (void*)out);
}